// Round 9
// baseline (339.532 us; speedup 1.0000x reference)
//
#include <hip/hip_runtime.h>
#include <math.h>

#define NHQ 32
#define NKV 8
#define HD 64
#define QKV_DIM 3072   // (32 + 2*8) * 64
#define MODEL_DIM 2048
#define QSCALE 0.1803368801111204f   // 0.125 * log2(e): folds attn scale + exp2 conversion

typedef __attribute__((ext_vector_type(4))) float     f32x4;
typedef __attribute__((ext_vector_type(8))) _Float16  half8;
typedef __attribute__((ext_vector_type(4))) _Float16  half4v;
typedef __attribute__((ext_vector_type(2))) __fp16    fp16x2;
typedef __attribute__((ext_vector_type(4))) unsigned  uint32x4;

#define ASYNC_COPY16(g, l)                                                        \
    __builtin_amdgcn_global_load_lds(                                             \
        (const __attribute__((address_space(1))) void*)(g),                       \
        (__attribute__((address_space(3))) void*)(l), 16, 0, 0)

__device__ __forceinline__ float fast_exp2(float x)
{
#if __has_builtin(__builtin_amdgcn_exp2f)
    return __builtin_amdgcn_exp2f(x);
#else
    float r;
    asm volatile("v_exp_f32 %0, %1\ns_nop 0" : "=v"(r) : "v"(x));
    return r;
#endif
}

// ---------------------------------------------------------------------------
// prep: fused fp32->f16 converts (3 tensors) + RoPE cos/sin table (one launch)
// ---------------------------------------------------------------------------
__global__ __launch_bounds__(256)
void prep_kernel(const float* __restrict__ s0, _Float16* __restrict__ d0, int n0,
                 const float* __restrict__ s1, _Float16* __restrict__ d1, int n1,
                 const float* __restrict__ s2, _Float16* __restrict__ d2, int n2,
                 const int* __restrict__ pos, float* __restrict__ tab, int ns)
{
    int j = blockIdx.x * 256 + threadIdx.x;
    if (j < n0 + n1 + n2) {
        const float* s; _Float16* d;
        if (j < n0)           { s = s0; d = d0; }
        else if (j < n0 + n1) { s = s1; d = d1; j -= n0; }
        else                  { s = s2; d = d2; j -= n0 + n1; }
        float4 v = ((const float4*)s)[j];
        half4v h = { (_Float16)v.x, (_Float16)v.y, (_Float16)v.z, (_Float16)v.w };
        ((half4v*)d)[j] = h;
    } else {
        j -= n0 + n1 + n2;
        if (j < ns) {
            int s = j >> 5, fi = j & 31;
            float p = (float)pos[s];
            float inv_freq = powf(150000.0f, -(float)fi * (1.0f / 32.0f));
            float ang = p * inv_freq;
            tab[s * 64 + fi]      = cosf(ang);
            tab[s * 64 + 32 + fi] = sinf(ang);
        }
    }
}

// ---------------------------------------------------------------------------
// f16 MFMA GEMM: C[M,N] = A[M,K] @ W[N,K]^T + bias[N]
// MODE 0: fp32 out. MODE 2: f16 out + fused RoPE epilogue.
//
// r9: phase-split 256x256 port of the 8-phase template (T3+T4+T5):
// BK=64, 8 waves (512 thr), per-wave 128x64 C (acc[8][4]), 2 LDS dbuf
// (128 KB, 1 block/CU). Per K-tile: 4 quadrant phases, each
//   { ds_read frags | 2 x global_load_lds staged -> s_barrier ->
//     lgkmcnt(0)+sched_barrier -> setprio(1) 16 MFMA setprio(0) -> s_barrier }
// One counted s_waitcnt vmcnt(2) per K-tile (phase 4), never 0 mid-loop.
//
// Staging is sub-buffer granular (race-audited):
//   tile T reads buf cur=T&1; quadrant order Q00,Q01,Q10,Q11:
//     A rows p0/p2 (qm=0) last read at P2 -> restaged (tile T+2) at P4
//     A rows p1/p3 (qm=1) last read at P4 -> staged (tile T+1) at P1
//     B fully read at P4 -> staged (tile T+1) at P2,P3
//   wait: at end-P4 all staging older than P4's 2 calls must land -> vmcnt(2).
// LDS layout [256][64] f16, 8x16B chunks/row, chunk XOR swizzle:
//   physical chunk = logical ^ (row&7)  (write side realized on global src;
//   read side physical = (kk*4+quad) ^ (l15&7)) -> 2-way conflicts (free).
// ---------------------------------------------------------------------------
template<int MODE>
__global__ __launch_bounds__(512, 2)
void gemm_f16_mfma(const _Float16* __restrict__ A, const _Float16* __restrict__ W,
                   const float* __restrict__ bias, void* __restrict__ Cout,
                   const float* __restrict__ tab, int M, int N, int K, int S)
{
    __shared__ _Float16 As[2][256 * 64];
    __shared__ _Float16 Bs[2][256 * 64];

    const int t    = threadIdx.x;          // 0..511
    const int w    = t >> 6;               // 0..7
    const int lane = t & 63;
    const int quad = lane >> 4, l15 = lane & 15;
    const size_t m0 = (size_t)blockIdx.y * 256;
    const size_t n0 = (size_t)blockIdx.x * 256;
    const int wm = (w >> 2) * 128;         // 2 m-wave groups
    const int wn = (w & 3) * 64;           // 4 n-wave groups

    // staging: call p covers rows 64p..64p+63; this thread's row-in-block-of-64
    // = w*8 + (lane>>3); it fetches logical chunk (lane&7)^((lane>>3)&7).
    const int srow = w * 8 + (lane >> 3);
    const int sco  = ((lane & 7) ^ ((lane >> 3) & 7)) << 3;
    const _Float16* aS = A + (m0 + srow) * K + sco;
    const _Float16* bS = W + (n0 + srow) * K + sco;

    const int xsel = l15 & 7;              // read-side XOR selector

    f32x4 acc[8][4];
#pragma unroll
    for (int i = 0; i < 8; i++)
#pragma unroll
        for (int j = 0; j < 4; j++) acc[i][j] = (f32x4){0.f, 0.f, 0.f, 0.f};

    const int NT = K >> 6;                 // 64-wide K tiles (2048 -> 32)

#define STG_A(bi, T_, p) ASYNC_COPY16(aS + (size_t)(64 * (p)) * K + (T_) * 64,    \
                                      &As[bi][((p) * 512 + w * 64) * 8])
#define STG_B(bi, T_, p) ASYNC_COPY16(bS + (size_t)(64 * (p)) * K + (T_) * 64,    \
                                      &Bs[bi][((p) * 512 + w * 64) * 8])

#define LDA(cur, QM)                                                              \
    do {                                                                          \
        _Pragma("unroll")                                                         \
        for (int i = 0; i < 4; i++) {                                             \
            _Pragma("unroll")                                                     \
            for (int kk = 0; kk < 2; kk++)                                        \
                fa[i][kk] = *(const half8*)&As[cur][                              \
                    (wm + ((QM) * 4 + i) * 16 + l15) * 64 +                       \
                    ((kk * 4 + quad) ^ xsel) * 8];                                \
        }                                                                         \
    } while (0)

#define LDB(cur, J0)                                                              \
    do {                                                                          \
        _Pragma("unroll")                                                         \
        for (int jj = 0; jj < 2; jj++) {                                          \
            _Pragma("unroll")                                                     \
            for (int kk = 0; kk < 2; kk++)                                        \
                fb[(J0) + jj][kk] = *(const half8*)&Bs[cur][                      \
                    (wn + ((J0) + jj) * 16 + l15) * 64 +                          \
                    ((kk * 4 + quad) ^ xsel) * 8];                                \
        }                                                                         \
    } while (0)

#define MM16(QM, J0)                                                              \
    do {                                                                          \
        __builtin_amdgcn_s_setprio(1);                                            \
        _Pragma("unroll")                                                         \
        for (int i = 0; i < 4; i++)                                               \
            _Pragma("unroll")                                                     \
            for (int jj = 0; jj < 2; jj++)                                        \
                _Pragma("unroll")                                                 \
                for (int kk = 0; kk < 2; kk++)                                    \
                    acc[(QM) * 4 + i][(J0) + jj] =                                \
                        __builtin_amdgcn_mfma_f32_16x16x32_f16(                   \
                            fa[i][kk], fb[(J0) + jj][kk],                         \
                            acc[(QM) * 4 + i][(J0) + jj], 0, 0, 0);               \
        __builtin_amdgcn_s_setprio(0);                                            \
    } while (0)

#define PHASE_SYNC                                                                \
    do {                                                                          \
        __builtin_amdgcn_sched_barrier(0);                                        \
        __builtin_amdgcn_s_barrier();                                             \
        asm volatile("s_waitcnt lgkmcnt(0)" ::: "memory");                        \
        __builtin_amdgcn_sched_barrier(0);                                        \
    } while (0)

    // ---- prologue: tile 0 fully staged + tile 1's A-p0,p2; wait; barrier ----
    STG_A(0, 0, 0); STG_A(0, 0, 1); STG_A(0, 0, 2); STG_A(0, 0, 3);
    STG_B(0, 0, 0); STG_B(0, 0, 1); STG_B(0, 0, 2); STG_B(0, 0, 3);
    if (NT > 1) {
        STG_A(1, 1, 0); STG_A(1, 1, 2);
        asm volatile("s_waitcnt vmcnt(2)" ::: "memory");
    } else {
        asm volatile("s_waitcnt vmcnt(0)" ::: "memory");
    }
    __builtin_amdgcn_s_barrier();
    __builtin_amdgcn_sched_barrier(0);

    half8 fa[4][2], fb[4][2];

    for (int T = 0; T < NT; ++T) {
        const int cur = T & 1;
        const int nxt = cur ^ 1;

        // ---- P1 (Q00): A[0..3], B[0..1]; stage T+1 A-p1,p3 ----
        LDA(cur, 0);
        LDB(cur, 0);
        if (T + 1 < NT) { STG_A(nxt, T + 1, 1); STG_A(nxt, T + 1, 3); }
        PHASE_SYNC;
        MM16(0, 0);
        __builtin_amdgcn_s_barrier();

        // ---- P2 (Q01): B[2..3]; stage T+1 B-p0,p1 ----
        LDB(cur, 2);
        if (T + 1 < NT) { STG_B(nxt, T + 1, 0); STG_B(nxt, T + 1, 1); }
        PHASE_SYNC;
        MM16(0, 2);
        __builtin_amdgcn_s_barrier();

        // ---- P3 (Q10): A[4..7]; stage T+1 B-p2,p3 ----
        LDA(cur, 1);
        if (T + 1 < NT) { STG_B(nxt, T + 1, 2); STG_B(nxt, T + 1, 3); }
        PHASE_SYNC;
        MM16(1, 0);
        __builtin_amdgcn_s_barrier();

        // ---- P4 (Q11): no new reads; stage T+2 A-p0,p2 into buf cur ----
        // (A rows p0/p2 of buf cur were last read at P2; barrier-separated.)
        if (T + 2 < NT) { STG_A(cur, T + 2, 0); STG_A(cur, T + 2, 2); }
        __builtin_amdgcn_sched_barrier(0);
        MM16(1, 2);
        if (T + 1 < NT) {
            if (T + 2 < NT) asm volatile("s_waitcnt vmcnt(2)" ::: "memory");
            else            asm volatile("s_waitcnt vmcnt(0)" ::: "memory");
            __builtin_amdgcn_s_barrier();
            __builtin_amdgcn_sched_barrier(0);
        }
    }
#undef STG_A
#undef STG_B
#undef LDA
#undef LDB
#undef MM16
#undef PHASE_SYNC

    // ---- epilogue: bias (+ RoPE for MODE 2), store ----
    float bv[4];
#pragma unroll
    for (int j = 0; j < 4; j++) bv[j] = bias[n0 + wn + j * 16 + l15];

    const int ct = (int)(((n0 + wn) >> 6) % 6);   // head-64 chunk type

#pragma unroll
    for (int i = 0; i < 8; i++)
#pragma unroll
        for (int r = 0; r < 4; r++) {
            const size_t row = m0 + wm + i * 16 + quad * 4 + r;
            float v[4];
#pragma unroll
            for (int j = 0; j < 4; j++) v[j] = acc[i][j][r] + bv[j];

            if (MODE == 2 && ct != 5) {
                const float* tc = tab + (size_t)(row % S) * 64;
                const float ca = tc[l15],      sa = tc[32 + l15];
                const float cb = tc[16 + l15], sb = tc[48 + l15];
                const float qs = (ct < 4) ? QSCALE : 1.0f;
                const float n0v = v[0] * ca - v[2] * sa;
                const float n1v = v[1] * cb - v[3] * sb;
                const float n2v = v[2] * ca + v[0] * sa;
                const float n3v = v[3] * cb + v[1] * sb;
                v[0] = n0v * qs; v[1] = n1v * qs; v[2] = n2v * qs; v[3] = n3v * qs;
            }

            const size_t col = n0 + wn + l15;
#pragma unroll
            for (int j = 0; j < 4; j++) {
                if (MODE != 0) ((_Float16*)Cout)[row * N + col + j * 16] = (_Float16)v[j];
                else           ((float*)Cout)[row * N + col + j * 16] = v[j];
            }
        }
}

// ---------------------------------------------------------------------------
// V transpose: qkv V-chunks [token][g-chunk 64] -> vtg[(g*64 + d)*BS + token].
// ---------------------------------------------------------------------------
__global__ __launch_bounds__(256)
void transpose_v_kernel(const _Float16* __restrict__ qkv, _Float16* __restrict__ vtg, int BS)
{
    __shared__ _Float16 tile[64 * 72];
    const int t = threadIdx.x;
    const int tb = blockIdx.x * 64;
    const int g = blockIdx.y;
    const int voff = (g * 6 + 5) * 64;

    const int tok = t >> 2, dsub = (t & 3) * 16;
    const _Float16* src = qkv + (size_t)(tb + tok) * QKV_DIM + voff + dsub;
    *(half8*)&tile[tok * 72 + dsub]     = *(const half8*)(src);
    *(half8*)&tile[tok * 72 + dsub + 8] = *(const half8*)(src + 8);
    __syncthreads();

    const int d = t >> 2, tsub = (t & 3) * 16;
    half8 a, c;
#pragma unroll
    for (int i = 0; i < 8; i++) a[i] = tile[(tsub + i) * 72 + d];
#pragma unroll
    for (int i = 0; i < 8; i++) c[i] = tile[(tsub + 8 + i) * 72 + d];
    _Float16* dst = vtg + ((size_t)g * 64 + d) * BS + tb + tsub;
    *(half8*)dst       = a;
    *(half8*)(dst + 8) = c;
}

// ---------------------------------------------------------------------------
// MFMA flash attention, no-max exp2 softmax, register-prefetched staging.
// EXACT r3 kernel (89.8-92.8 us proven; r4/r8 dbuf variants both regressed):
// single-buffer Ks/VsT, 2 barriers/tile, T12 in-register P (permlane swaps),
// constant ones-fragment L, no setprio. FINAL form for attn.
// ---------------------------------------------------------------------------
__global__ __launch_bounds__(256)
void attn_mfma(const _Float16* __restrict__ qkv, const _Float16* __restrict__ vtg,
               _Float16* __restrict__ out, int B, int S)
{
    __shared__ _Float16 Ks[64 * 72];       // [key][d] stride 72
    __shared__ _Float16 VsT[64 * 72];      // [d][key] stride 72

    const int t = threadIdx.x, w = t >> 6, lane = t & 63;
    const int quad = lane >> 4, l15 = lane & 15;
    const int b = blockIdx.z, g = blockIdx.y;
    const int q0 = blockIdx.x * 32;
    const int qoff = (g * 6 + w) * 64;
    const int koff = (g * 6 + 4) * 64;

    half8 qf[2][2];
#pragma unroll
    for (int s = 0; s < 2; s++) {
        const _Float16* qp = qkv + (size_t)(b * S + q0 + s * 16 + l15) * QKV_DIM + qoff;
        qf[s][0] = *(const half8*)(qp + quad * 8);
        qf[s][1] = *(const half8*)(qp + 32 + quad * 8);
    }

    half8 lv;
    {
        const _Float16 one = (l15 == 0) ? (_Float16)1.0f : (_Float16)0.0f;
#pragma unroll
        for (int j = 0; j < 8; j++) lv[j] = one;
    }

    f32x4 O[2][4], L[2];
#pragma unroll
    for (int s = 0; s < 2; s++) {
        L[s] = (f32x4){0.f, 0.f, 0.f, 0.f};
#pragma unroll
        for (int dt = 0; dt < 4; dt++) O[s][dt] = (f32x4){0.f, 0.f, 0.f, 0.f};
    }

    const int kst_tok = t >> 2;
    const int kst_d   = (t & 3) * 16;
    const int vst_d   = t >> 3;
    const int vst_sub = (t & 7) * 8;

    const _Float16* kbase  = qkv + (size_t)(b * S + kst_tok) * QKV_DIM + koff + kst_d;
    const _Float16* vbase0 = vtg + ((size_t)g * 64 + vst_d) * (size_t)(B * S) + b * S + vst_sub;
    const _Float16* vbase1 = vtg + ((size_t)g * 64 + 32 + vst_d) * (size_t)(B * S) + b * S + vst_sub;

    half8 kr0 = *(const half8*)(kbase);
    half8 kr1 = *(const half8*)(kbase + 8);
    half8 vr0 = *(const half8*)(vbase0);
    half8 vr1 = *(const half8*)(vbase1);

    for (int kt = 0; kt < S; kt += 64) {
        *(half8*)&Ks[kst_tok * 72 + kst_d]         = kr0;
        *(half8*)&Ks[kst_tok * 72 + kst_d + 8]     = kr1;
        *(half8*)&VsT[vst_d * 72 + vst_sub]        = vr0;
        *(half8*)&VsT[(32 + vst_d) * 72 + vst_sub] = vr1;
        __syncthreads();

        if (kt + 64 < S) {
            kr0 = *(const half8*)(kbase + (size_t)(kt + 64) * QKV_DIM);
            kr1 = *(const half8*)(kbase + (size_t)(kt + 64) * QKV_DIM + 8);
            vr0 = *(const half8*)(vbase0 + kt + 64);
            vr1 = *(const half8*)(vbase1 + kt + 64);
        }

        half8 kf[4][2];
#pragma unroll
        for (int mt = 0; mt < 4; mt++) {
            kf[mt][0] = *(const half8*)&Ks[(mt * 16 + l15) * 72 + quad * 8];
            kf[mt][1] = *(const half8*)&Ks[(mt * 16 + l15) * 72 + 32 + quad * 8];
        }

        half8 pf[2][2];
#pragma unroll
        for (int s = 0; s < 2; s++) {
            f32x4 sacc[4];
#pragma unroll
            for (int mt = 0; mt < 4; mt++) {
                f32x4 z = (f32x4){0.f, 0.f, 0.f, 0.f};
                z = __builtin_amdgcn_mfma_f32_16x16x32_f16(kf[mt][0], qf[s][0], z, 0, 0, 0);
                z = __builtin_amdgcn_mfma_f32_16x16x32_f16(kf[mt][1], qf[s][1], z, 0, 0, 0);
                sacc[mt] = z;
            }

            unsigned u[4][2];
#pragma unroll
            for (int mt = 0; mt < 4; mt++) {
                fp16x2 pa = __builtin_amdgcn_cvt_pkrtz(fast_exp2(sacc[mt][0]),
                                                       fast_exp2(sacc[mt][1]));
                fp16x2 pb = __builtin_amdgcn_cvt_pkrtz(fast_exp2(sacc[mt][2]),
                                                       fast_exp2(sacc[mt][3]));
                u[mt][0] = __builtin_bit_cast(unsigned, pa);
                u[mt][1] = __builtin_bit_cast(unsigned, pb);
            }

#pragma unroll
            for (int h = 0; h < 2; h++) {
                uint32x4 pw;
#pragma unroll
                for (int c = 0; c < 2; c++) {
                    unsigned x = u[h * 2][c], y = u[h * 2 + 1][c];
                    asm("v_permlane32_swap_b32 %0, %1" : "+v"(x), "+v"(y));
                    asm("v_permlane16_swap_b32 %0, %1" : "+v"(x), "+v"(y));
                    pw[c]     = x;
                    pw[2 + c] = y;
                }
                pf[s][h] = __builtin_bit_cast(half8, pw);
            }
        }

#pragma unroll
        for (int dt = 0; dt < 4; dt++) {
            half8 vv0 = *(const half8*)&VsT[(dt * 16 + l15) * 72 + quad * 8];
            half8 vv1 = *(const half8*)&VsT[(dt * 16 + l15) * 72 + 32 + quad * 8];
#pragma unroll
            for (int s = 0; s < 2; s++) {
                O[s][dt] = __builtin_amdgcn_mfma_f32_16x16x32_f16(pf[s][0], vv0, O[s][dt], 0, 0, 0);
                O[s][dt] = __builtin_amdgcn_mfma_f32_16x16x32_f16(pf[s][1], vv1, O[s][dt], 0, 0, 0);
            }
        }
#pragma unroll
        for (int s = 0; s < 2; s++) {
            L[s] = __builtin_amdgcn_mfma_f32_16x16x32_f16(pf[s][0], lv, L[s], 0, 0, 0);
            L[s] = __builtin_amdgcn_mfma_f32_16x16x32_f16(pf[s][1], lv, L[s], 0, 0, 0);
        }
        __syncthreads();
    }

    const int hq = g * 4 + w;
#pragma unroll
    for (int s = 0; s < 2; s++)
#pragma unroll
        for (int r = 0; r < 4; r++) {
            const float lr = __shfl(L[s][r], lane & 48, 64);
            const float ir = 1.0f / lr;
            const size_t row = (size_t)(b * S + q0 + s * 16 + quad * 4 + r);
#pragma unroll
            for (int dt = 0; dt < 4; dt++)
                out[row * (NHQ * HD) + hq * 64 + dt * 16 + l15] = (_Float16)(O[s][dt][r] * ir);
        }
}

// ---------------------------------------------------------------------------
extern "C" void kernel_launch(void* const* d_in, const int* in_sizes, int n_in,
                              void* d_out, int out_size, void* d_ws, size_t ws_size,
                              hipStream_t stream)
{
    const float* hidden = (const float*)d_in[0];
    const int*   pos    = (const int*)d_in[1];
    const float* qkv_w  = (const float*)d_in[2];
    const float* qkv_b  = (const float*)d_in[3];
    const float* o_w    = (const float*)d_in[4];
    const float* o_b    = (const float*)d_in[5];
    float* out = (float*)d_out;

    const int S  = in_sizes[1];                 // 2048
    const int BS = in_sizes[0] / MODEL_DIM;     // 4096
    const int B  = BS / S;                      // 2

    _Float16* hA   = (_Float16*)d_ws;                      // [BS, 2048]
    _Float16* hW1  = hA   + (size_t)BS * MODEL_DIM;        // [3072, 2048]
    _Float16* hW2  = hW1  + (size_t)QKV_DIM * MODEL_DIM;   // [2048, 2048]
    _Float16* qkvh = hW2  + (size_t)MODEL_DIM * MODEL_DIM; // [BS, 3072]
    _Float16* atth = qkvh + (size_t)BS * QKV_DIM;          // [BS, 2048]
    float*    tab  = (float*)(atth + (size_t)BS * MODEL_DIM); // [S, 64]
    _Float16* vtg  = (_Float16*)(tab + (size_t)S * 64);    // [NKV*64, BS]

    // 0) fused fp32 -> f16 converts + rope table (one launch)
    const int n0 = BS * MODEL_DIM / 4;
    const int n1 = QKV_DIM * MODEL_DIM / 4;
    const int n2 = MODEL_DIM * MODEL_DIM / 4;
    const int ns = S * 32;
    prep_kernel<<<(n0 + n1 + n2 + ns + 255) / 256, 256, 0, stream>>>(
        hidden, hA, n0, qkv_w, hW1, n1, o_w, hW2, n2, pos, tab, ns);

    // 1) QKV projection with fused RoPE (+0.125*log2e on Q)  [256x256 tiles]
    gemm_f16_mfma<2><<<dim3(QKV_DIM / 256, BS / 256), 512, 0, stream>>>(
        hA, hW1, qkv_b, qkvh, tab, BS, QKV_DIM, MODEL_DIM, S);

    // 1b) V transpose -> vtg
    transpose_v_kernel<<<dim3(BS / 64, NKV), 256, 0, stream>>>(qkvh, vtg, BS);

    // 2) Attention -> atth [BS, 2048]
    attn_mfma<<<dim3(S / 32, NKV, B), 256, 0, stream>>>(qkvh, vtg, atth, B, S);

    // 3) Output projection (fp32 out)  [256x256 tiles]
    gemm_f16_mfma<0><<<dim3(MODEL_DIM / 256, BS / 256), 512, 0, stream>>>(
        atth, hW2, o_b, out, nullptr, BS, MODEL_DIM, MODEL_DIM, S);
}

// Round 10
// 319.678 us; speedup vs baseline: 1.0621x; 1.0621x over previous
//
#include <hip/hip_runtime.h>
#include <math.h>

#define NHQ 32
#define NKV 8
#define HD 64
#define QKV_DIM 3072   // (32 + 2*8) * 64
#define MODEL_DIM 2048
#define QSCALE 0.1803368801111204f   // 0.125 * log2(e): folds attn scale + exp2 conversion

typedef __attribute__((ext_vector_type(4))) float     f32x4;
typedef __attribute__((ext_vector_type(8))) _Float16  half8;
typedef __attribute__((ext_vector_type(4))) _Float16  half4v;
typedef __attribute__((ext_vector_type(2))) __fp16    fp16x2;
typedef __attribute__((ext_vector_type(4))) unsigned  uint32x4;

#define ASYNC_COPY16(g, l)                                                        \
    __builtin_amdgcn_global_load_lds(                                             \
        (const __attribute__((address_space(1))) void*)(g),                       \
        (__attribute__((address_space(3))) void*)(l), 16, 0, 0)

__device__ __forceinline__ float fast_exp2(float x)
{
#if __has_builtin(__builtin_amdgcn_exp2f)
    return __builtin_amdgcn_exp2f(x);
#else
    float r;
    asm volatile("v_exp_f32 %0, %1\ns_nop 0" : "=v"(r) : "v"(x));
    return r;
#endif
}

// ---------------------------------------------------------------------------
// prep: fused fp32->f16 converts (3 tensors) + RoPE cos/sin table (one launch)
// ---------------------------------------------------------------------------
__global__ __launch_bounds__(256)
void prep_kernel(const float* __restrict__ s0, _Float16* __restrict__ d0, int n0,
                 const float* __restrict__ s1, _Float16* __restrict__ d1, int n1,
                 const float* __restrict__ s2, _Float16* __restrict__ d2, int n2,
                 const int* __restrict__ pos, float* __restrict__ tab, int ns)
{
    int j = blockIdx.x * 256 + threadIdx.x;
    if (j < n0 + n1 + n2) {
        const float* s; _Float16* d;
        if (j < n0)           { s = s0; d = d0; }
        else if (j < n0 + n1) { s = s1; d = d1; j -= n0; }
        else                  { s = s2; d = d2; j -= n0 + n1; }
        float4 v = ((const float4*)s)[j];
        half4v h = { (_Float16)v.x, (_Float16)v.y, (_Float16)v.z, (_Float16)v.w };
        ((half4v*)d)[j] = h;
    } else {
        j -= n0 + n1 + n2;
        if (j < ns) {
            int s = j >> 5, fi = j & 31;
            float p = (float)pos[s];
            float inv_freq = powf(150000.0f, -(float)fi * (1.0f / 32.0f));
            float ang = p * inv_freq;
            tab[s * 64 + fi]      = cosf(ang);
            tab[s * 64 + 32 + fi] = sinf(ang);
        }
    }
}

// ---------------------------------------------------------------------------
// f16 MFMA GEMM: C[M,N] = A[M,K] @ W[N,K]^T + bias[N]
// MODE 0: fp32 out. MODE 2: f16 out + fused RoPE epilogue + fused V-transpose.
// EXACT r3 ring (proven best of 6 structures tried: r5 256², r6 128x256,
// r7 read-ahead 4-ring, r9 phase-split all regressed or tied):
// 128x128 tile, 4 waves, 3-stage LDS ring, one barrier per K-step with
// counted vmcnt(4), k-chunk XOR swizzle. LDS 48KB -> 3 blocks/CU.
//
// r10: for MODE 2, V-chunk waves (ct==5) scatter their epilogue registers
// DIRECTLY to vtg[(g*64+d)*M + token] (d = l15+j*16, token = row), replacing
// the separate transpose kernel (one fewer launch; V never round-trips
// through qkvh).
// ---------------------------------------------------------------------------
template<int MODE>
__global__ __launch_bounds__(256, 3)
void gemm_f16_mfma(const _Float16* __restrict__ A, const _Float16* __restrict__ W,
                   const float* __restrict__ bias, void* __restrict__ Cout,
                   const float* __restrict__ tab, _Float16* __restrict__ vtg,
                   int M, int N, int K, int S)
{
    __shared__ _Float16 As[3][128 * 32];
    __shared__ _Float16 Bs[3][128 * 32];

    const int t    = threadIdx.x;
    const int w    = t >> 6;
    const int lane = t & 63;
    const int quad = lane >> 4, l15 = lane & 15;
    const size_t m0 = (size_t)blockIdx.y * 128;
    const size_t n0 = (size_t)blockIdx.x * 128;
    const int wm = (w >> 1) * 64, wn = (w & 1) * 64;

    const int sr   = t >> 2;
    const int klog = ((t & 3) ^ ((sr >> 1) & 3)) * 8;
    const _Float16* ag0 = A + (m0 + sr) * K + klog;
    const _Float16* ag1 = A + (m0 + 64 + sr) * K + klog;
    const _Float16* bg0 = W + (n0 + sr) * K + klog;
    const _Float16* bg1 = W + (n0 + 64 + sr) * K + klog;

    const int xk8 = (quad ^ ((l15 >> 1) & 3)) * 8;

    f32x4 acc[4][4];
#pragma unroll
    for (int i = 0; i < 4; i++)
#pragma unroll
        for (int j = 0; j < 4; j++) acc[i][j] = (f32x4){0.f, 0.f, 0.f, 0.f};

    const int nkt = K >> 5;   // K/32 tiles

#define STAGE_TILE(bi, kt_)                                         \
    do {                                                            \
        const int _k0 = (kt_) * 32;                                 \
        ASYNC_COPY16(ag0 + _k0, &As[bi][w * 512]);                  \
        ASYNC_COPY16(ag1 + _k0, &As[bi][2048 + w * 512]);           \
        ASYNC_COPY16(bg0 + _k0, &Bs[bi][w * 512]);                  \
        ASYNC_COPY16(bg1 + _k0, &Bs[bi][2048 + w * 512]);           \
    } while (0)

    STAGE_TILE(0, 0);
    STAGE_TILE(1, 1);
    asm volatile("s_waitcnt vmcnt(4)" ::: "memory");
    __builtin_amdgcn_s_barrier();
    __builtin_amdgcn_sched_barrier(0);

    int bc = 0;   // buffer holding tile kt
    for (int kt = 0; kt < nkt; ++kt) {
        const _Float16* Ab = &As[bc][0];
        const _Float16* Bb = &Bs[bc][0];

        half8 af[4], bf[4];
#pragma unroll
        for (int i = 0; i < 4; i++) {
            af[i] = *(const half8*)(Ab + (wm + i * 16 + l15) * 32 + xk8);
            bf[i] = *(const half8*)(Bb + (wn + i * 16 + l15) * 32 + xk8);
        }

        if (kt + 2 < nkt) {
            int bs = bc + 2; if (bs >= 3) bs -= 3;
            STAGE_TILE(bs, kt + 2);
        }

        __builtin_amdgcn_s_setprio(1);
#pragma unroll
        for (int i = 0; i < 4; i++)
#pragma unroll
            for (int j = 0; j < 4; j++)
                acc[i][j] = __builtin_amdgcn_mfma_f32_16x16x32_f16(af[i], bf[j], acc[i][j], 0, 0, 0);
        __builtin_amdgcn_s_setprio(0);

        if (kt + 1 < nkt) {
            if (kt + 2 < nkt) asm volatile("s_waitcnt vmcnt(4)" ::: "memory");
            else              asm volatile("s_waitcnt vmcnt(0)" ::: "memory");
            __builtin_amdgcn_s_barrier();
            __builtin_amdgcn_sched_barrier(0);
        }
        bc = bc + 1; if (bc == 3) bc = 0;
    }
#undef STAGE_TILE

    float bv[4];
#pragma unroll
    for (int j = 0; j < 4; j++) bv[j] = bias[n0 + wn + j * 16 + l15];

    // chunk type: head-64 col block; ct%6 in {0..3}=q, 4=k, 5=v
    const int ct  = (int)(((n0 + wn) >> 6) % 6);
    const int gkv = (int)(((n0 + wn) >> 6) / 6);
    _Float16* vchunk = (MODE == 2) ? (vtg + (size_t)gkv * 64 * M) : nullptr;

#pragma unroll
    for (int i = 0; i < 4; i++)
#pragma unroll
        for (int r = 0; r < 4; r++) {
            const size_t row = m0 + wm + i * 16 + quad * 4 + r;
            float v[4];
#pragma unroll
            for (int j = 0; j < 4; j++) v[j] = acc[i][j][r] + bv[j];

            if (MODE == 2 && ct != 5) {
                const float* tc = tab + (size_t)(row % S) * 64;
                const float ca = tc[l15],      sa = tc[32 + l15];
                const float cb = tc[16 + l15], sb = tc[48 + l15];
                const float qs = (ct < 4) ? QSCALE : 1.0f;
                const float n0v = v[0] * ca - v[2] * sa;
                const float n1v = v[1] * cb - v[3] * sb;
                const float n2v = v[2] * ca + v[0] * sa;
                const float n3v = v[3] * cb + v[1] * sb;
                v[0] = n0v * qs; v[1] = n1v * qs; v[2] = n2v * qs; v[3] = n3v * qs;
            }

            if (MODE == 2 && ct == 5) {
                // fused V transpose: vtg[(gkv*64 + d)*M + token], d = l15+j*16
#pragma unroll
                for (int j = 0; j < 4; j++)
                    vchunk[(size_t)(l15 + j * 16) * M + row] = (_Float16)v[j];
            } else {
                const size_t col = n0 + wn + l15;
#pragma unroll
                for (int j = 0; j < 4; j++) {
                    if (MODE != 0) ((_Float16*)Cout)[row * N + col + j * 16] = (_Float16)v[j];
                    else           ((float*)Cout)[row * N + col + j * 16] = v[j];
                }
            }
        }
}

// ---------------------------------------------------------------------------
// MFMA flash attention, no-max exp2 softmax, register-prefetched staging.
// EXACT r3 kernel (89.8-92.8 us proven; r4/r8 dbuf variants both regressed):
// single-buffer Ks/VsT, 2 barriers/tile, T12 in-register P (permlane swaps),
// constant ones-fragment L, no setprio. FINAL form for attn.
// ---------------------------------------------------------------------------
__global__ __launch_bounds__(256)
void attn_mfma(const _Float16* __restrict__ qkv, const _Float16* __restrict__ vtg,
               _Float16* __restrict__ out, int B, int S)
{
    __shared__ _Float16 Ks[64 * 72];       // [key][d] stride 72
    __shared__ _Float16 VsT[64 * 72];      // [d][key] stride 72

    const int t = threadIdx.x, w = t >> 6, lane = t & 63;
    const int quad = lane >> 4, l15 = lane & 15;
    const int b = blockIdx.z, g = blockIdx.y;
    const int q0 = blockIdx.x * 32;
    const int qoff = (g * 6 + w) * 64;
    const int koff = (g * 6 + 4) * 64;

    half8 qf[2][2];
#pragma unroll
    for (int s = 0; s < 2; s++) {
        const _Float16* qp = qkv + (size_t)(b * S + q0 + s * 16 + l15) * QKV_DIM + qoff;
        qf[s][0] = *(const half8*)(qp + quad * 8);
        qf[s][1] = *(const half8*)(qp + 32 + quad * 8);
    }

    half8 lv;
    {
        const _Float16 one = (l15 == 0) ? (_Float16)1.0f : (_Float16)0.0f;
#pragma unroll
        for (int j = 0; j < 8; j++) lv[j] = one;
    }

    f32x4 O[2][4], L[2];
#pragma unroll
    for (int s = 0; s < 2; s++) {
        L[s] = (f32x4){0.f, 0.f, 0.f, 0.f};
#pragma unroll
        for (int dt = 0; dt < 4; dt++) O[s][dt] = (f32x4){0.f, 0.f, 0.f, 0.f};
    }

    const int kst_tok = t >> 2;
    const int kst_d   = (t & 3) * 16;
    const int vst_d   = t >> 3;
    const int vst_sub = (t & 7) * 8;

    const _Float16* kbase  = qkv + (size_t)(b * S + kst_tok) * QKV_DIM + koff + kst_d;
    const _Float16* vbase0 = vtg + ((size_t)g * 64 + vst_d) * (size_t)(B * S) + b * S + vst_sub;
    const _Float16* vbase1 = vtg + ((size_t)g * 64 + 32 + vst_d) * (size_t)(B * S) + b * S + vst_sub;

    half8 kr0 = *(const half8*)(kbase);
    half8 kr1 = *(const half8*)(kbase + 8);
    half8 vr0 = *(const half8*)(vbase0);
    half8 vr1 = *(const half8*)(vbase1);

    for (int kt = 0; kt < S; kt += 64) {
        *(half8*)&Ks[kst_tok * 72 + kst_d]         = kr0;
        *(half8*)&Ks[kst_tok * 72 + kst_d + 8]     = kr1;
        *(half8*)&VsT[vst_d * 72 + vst_sub]        = vr0;
        *(half8*)&VsT[(32 + vst_d) * 72 + vst_sub] = vr1;
        __syncthreads();

        if (kt + 64 < S) {
            kr0 = *(const half8*)(kbase + (size_t)(kt + 64) * QKV_DIM);
            kr1 = *(const half8*)(kbase + (size_t)(kt + 64) * QKV_DIM + 8);
            vr0 = *(const half8*)(vbase0 + kt + 64);
            vr1 = *(const half8*)(vbase1 + kt + 64);
        }

        half8 kf[4][2];
#pragma unroll
        for (int mt = 0; mt < 4; mt++) {
            kf[mt][0] = *(const half8*)&Ks[(mt * 16 + l15) * 72 + quad * 8];
            kf[mt][1] = *(const half8*)&Ks[(mt * 16 + l15) * 72 + 32 + quad * 8];
        }

        half8 pf[2][2];
#pragma unroll
        for (int s = 0; s < 2; s++) {
            f32x4 sacc[4];
#pragma unroll
            for (int mt = 0; mt < 4; mt++) {
                f32x4 z = (f32x4){0.f, 0.f, 0.f, 0.f};
                z = __builtin_amdgcn_mfma_f32_16x16x32_f16(kf[mt][0], qf[s][0], z, 0, 0, 0);
                z = __builtin_amdgcn_mfma_f32_16x16x32_f16(kf[mt][1], qf[s][1], z, 0, 0, 0);
                sacc[mt] = z;
            }

            unsigned u[4][2];
#pragma unroll
            for (int mt = 0; mt < 4; mt++) {
                fp16x2 pa = __builtin_amdgcn_cvt_pkrtz(fast_exp2(sacc[mt][0]),
                                                       fast_exp2(sacc[mt][1]));
                fp16x2 pb = __builtin_amdgcn_cvt_pkrtz(fast_exp2(sacc[mt][2]),
                                                       fast_exp2(sacc[mt][3]));
                u[mt][0] = __builtin_bit_cast(unsigned, pa);
                u[mt][1] = __builtin_bit_cast(unsigned, pb);
            }

#pragma unroll
            for (int h = 0; h < 2; h++) {
                uint32x4 pw;
#pragma unroll
                for (int c = 0; c < 2; c++) {
                    unsigned x = u[h * 2][c], y = u[h * 2 + 1][c];
                    asm("v_permlane32_swap_b32 %0, %1" : "+v"(x), "+v"(y));
                    asm("v_permlane16_swap_b32 %0, %1" : "+v"(x), "+v"(y));
                    pw[c]     = x;
                    pw[2 + c] = y;
                }
                pf[s][h] = __builtin_bit_cast(half8, pw);
            }
        }

#pragma unroll
        for (int dt = 0; dt < 4; dt++) {
            half8 vv0 = *(const half8*)&VsT[(dt * 16 + l15) * 72 + quad * 8];
            half8 vv1 = *(const half8*)&VsT[(dt * 16 + l15) * 72 + 32 + quad * 8];
#pragma unroll
            for (int s = 0; s < 2; s++) {
                O[s][dt] = __builtin_amdgcn_mfma_f32_16x16x32_f16(pf[s][0], vv0, O[s][dt], 0, 0, 0);
                O[s][dt] = __builtin_amdgcn_mfma_f32_16x16x32_f16(pf[s][1], vv1, O[s][dt], 0, 0, 0);
            }
        }
#pragma unroll
        for (int s = 0; s < 2; s++) {
            L[s] = __builtin_amdgcn_mfma_f32_16x16x32_f16(pf[s][0], lv, L[s], 0, 0, 0);
            L[s] = __builtin_amdgcn_mfma_f32_16x16x32_f16(pf[s][1], lv, L[s], 0, 0, 0);
        }
        __syncthreads();
    }

    const int hq = g * 4 + w;
#pragma unroll
    for (int s = 0; s < 2; s++)
#pragma unroll
        for (int r = 0; r < 4; r++) {
            const float lr = __shfl(L[s][r], lane & 48, 64);
            const float ir = 1.0f / lr;
            const size_t row = (size_t)(b * S + q0 + s * 16 + quad * 4 + r);
#pragma unroll
            for (int dt = 0; dt < 4; dt++)
                out[row * (NHQ * HD) + hq * 64 + dt * 16 + l15] = (_Float16)(O[s][dt][r] * ir);
        }
}

// ---------------------------------------------------------------------------
extern "C" void kernel_launch(void* const* d_in, const int* in_sizes, int n_in,
                              void* d_out, int out_size, void* d_ws, size_t ws_size,
                              hipStream_t stream)
{
    const float* hidden = (const float*)d_in[0];
    const int*   pos    = (const int*)d_in[1];
    const float* qkv_w  = (const float*)d_in[2];
    const float* qkv_b  = (const float*)d_in[3];
    const float* o_w    = (const float*)d_in[4];
    const float* o_b    = (const float*)d_in[5];
    float* out = (float*)d_out;

    const int S  = in_sizes[1];                 // 2048
    const int BS = in_sizes[0] / MODEL_DIM;     // 4096
    const int B  = BS / S;                      // 2

    _Float16* hA   = (_Float16*)d_ws;                      // [BS, 2048]
    _Float16* hW1  = hA   + (size_t)BS * MODEL_DIM;        // [3072, 2048]
    _Float16* hW2  = hW1  + (size_t)QKV_DIM * MODEL_DIM;   // [2048, 2048]
    _Float16* qkvh = hW2  + (size_t)MODEL_DIM * MODEL_DIM; // [BS, 3072]
    _Float16* atth = qkvh + (size_t)BS * QKV_DIM;          // [BS, 2048]
    float*    tab  = (float*)(atth + (size_t)BS * MODEL_DIM); // [S, 64]
    _Float16* vtg  = (_Float16*)(tab + (size_t)S * 64);    // [NKV*64, BS]

    // 0) fused fp32 -> f16 converts + rope table (one launch)
    const int n0 = BS * MODEL_DIM / 4;
    const int n1 = QKV_DIM * MODEL_DIM / 4;
    const int n2 = MODEL_DIM * MODEL_DIM / 4;
    const int ns = S * 32;
    prep_kernel<<<(n0 + n1 + n2 + ns + 255) / 256, 256, 0, stream>>>(
        hidden, hA, n0, qkv_w, hW1, n1, o_w, hW2, n2, pos, tab, ns);

    // 1) QKV projection: fused RoPE (+0.125*log2e on Q) + fused V transpose
    gemm_f16_mfma<2><<<dim3(QKV_DIM / 128, BS / 128), 256, 0, stream>>>(
        hA, hW1, qkv_b, qkvh, tab, vtg, BS, QKV_DIM, MODEL_DIM, S);

    // 2) Attention -> atth [BS, 2048]
    attn_mfma<<<dim3(S / 32, NKV, B), 256, 0, stream>>>(qkvh, vtg, atth, B, S);

    // 3) Output projection (fp32 out)
    gemm_f16_mfma<0><<<dim3(MODEL_DIM / 128, BS / 128), 256, 0, stream>>>(
        atth, hW2, o_b, out, nullptr, nullptr, BS, MODEL_DIM, MODEL_DIM, S);
}

// Round 11
// 318.158 us; speedup vs baseline: 1.0672x; 1.0048x over previous
//
#include <hip/hip_runtime.h>
#include <math.h>

#define NHQ 32
#define NKV 8
#define HD 64
#define QKV_DIM 3072   // (32 + 2*8) * 64
#define MODEL_DIM 2048
#define QSCALE 0.1803368801111204f   // 0.125 * log2(e): folds attn scale + exp2 conversion

typedef __attribute__((ext_vector_type(4))) float     f32x4;
typedef __attribute__((ext_vector_type(8))) _Float16  half8;
typedef __attribute__((ext_vector_type(4))) _Float16  half4v;
typedef __attribute__((ext_vector_type(2))) __fp16    fp16x2;
typedef __attribute__((ext_vector_type(4))) unsigned  uint32x4;

#define ASYNC_COPY16(g, l)                                                        \
    __builtin_amdgcn_global_load_lds(                                             \
        (const __attribute__((address_space(1))) void*)(g),                       \
        (__attribute__((address_space(3))) void*)(l), 16, 0, 0)

__device__ __forceinline__ float fast_exp2(float x)
{
#if __has_builtin(__builtin_amdgcn_exp2f)
    return __builtin_amdgcn_exp2f(x);
#else
    float r;
    asm volatile("v_exp_f32 %0, %1\ns_nop 0" : "=v"(r) : "v"(x));
    return r;
#endif
}

// ---------------------------------------------------------------------------
// prep: fused fp32->f16 converts (3 tensors) + RoPE cos/sin table (one launch)
// ---------------------------------------------------------------------------
__global__ __launch_bounds__(256)
void prep_kernel(const float* __restrict__ s0, _Float16* __restrict__ d0, int n0,
                 const float* __restrict__ s1, _Float16* __restrict__ d1, int n1,
                 const float* __restrict__ s2, _Float16* __restrict__ d2, int n2,
                 const int* __restrict__ pos, float* __restrict__ tab, int ns)
{
    int j = blockIdx.x * 256 + threadIdx.x;
    if (j < n0 + n1 + n2) {
        const float* s; _Float16* d;
        if (j < n0)           { s = s0; d = d0; }
        else if (j < n0 + n1) { s = s1; d = d1; j -= n0; }
        else                  { s = s2; d = d2; j -= n0 + n1; }
        float4 v = ((const float4*)s)[j];
        half4v h = { (_Float16)v.x, (_Float16)v.y, (_Float16)v.z, (_Float16)v.w };
        ((half4v*)d)[j] = h;
    } else {
        j -= n0 + n1 + n2;
        if (j < ns) {
            int s = j >> 5, fi = j & 31;
            float p = (float)pos[s];
            float inv_freq = powf(150000.0f, -(float)fi * (1.0f / 32.0f));
            float ang = p * inv_freq;
            tab[s * 64 + fi]      = cosf(ang);
            tab[s * 64 + 32 + fi] = sinf(ang);
        }
    }
}

// ---------------------------------------------------------------------------
// f16 MFMA GEMM: C[M,N] = A[M,K] @ W[N,K]^T + bias[N]
// MODE 0: fp32 out. MODE 2: f16 out + fused RoPE epilogue.
// EXACT r3 ring (proven best of 6 structures tried): 128x128 tile, 4 waves,
// 3-stage LDS ring, one barrier per K-step with counted vmcnt(4),
// k-chunk XOR swizzle. LDS 48KB -> 3 blocks/CU. FINAL form for GEMM.
// ---------------------------------------------------------------------------
template<int MODE>
__global__ __launch_bounds__(256, 3)
void gemm_f16_mfma(const _Float16* __restrict__ A, const _Float16* __restrict__ W,
                   const float* __restrict__ bias, void* __restrict__ Cout,
                   const float* __restrict__ tab, int M, int N, int K, int S)
{
    __shared__ _Float16 As[3][128 * 32];
    __shared__ _Float16 Bs[3][128 * 32];

    const int t    = threadIdx.x;
    const int w    = t >> 6;
    const int lane = t & 63;
    const int quad = lane >> 4, l15 = lane & 15;
    const size_t m0 = (size_t)blockIdx.y * 128;
    const size_t n0 = (size_t)blockIdx.x * 128;
    const int wm = (w >> 1) * 64, wn = (w & 1) * 64;

    const int sr   = t >> 2;
    const int klog = ((t & 3) ^ ((sr >> 1) & 3)) * 8;
    const _Float16* ag0 = A + (m0 + sr) * K + klog;
    const _Float16* ag1 = A + (m0 + 64 + sr) * K + klog;
    const _Float16* bg0 = W + (n0 + sr) * K + klog;
    const _Float16* bg1 = W + (n0 + 64 + sr) * K + klog;

    const int xk8 = (quad ^ ((l15 >> 1) & 3)) * 8;

    f32x4 acc[4][4];
#pragma unroll
    for (int i = 0; i < 4; i++)
#pragma unroll
        for (int j = 0; j < 4; j++) acc[i][j] = (f32x4){0.f, 0.f, 0.f, 0.f};

    const int nkt = K >> 5;   // K/32 tiles

#define STAGE_TILE(bi, kt_)                                         \
    do {                                                            \
        const int _k0 = (kt_) * 32;                                 \
        ASYNC_COPY16(ag0 + _k0, &As[bi][w * 512]);                  \
        ASYNC_COPY16(ag1 + _k0, &As[bi][2048 + w * 512]);           \
        ASYNC_COPY16(bg0 + _k0, &Bs[bi][w * 512]);                  \
        ASYNC_COPY16(bg1 + _k0, &Bs[bi][2048 + w * 512]);           \
    } while (0)

    STAGE_TILE(0, 0);
    STAGE_TILE(1, 1);
    asm volatile("s_waitcnt vmcnt(4)" ::: "memory");
    __builtin_amdgcn_s_barrier();
    __builtin_amdgcn_sched_barrier(0);

    int bc = 0;   // buffer holding tile kt
    for (int kt = 0; kt < nkt; ++kt) {
        const _Float16* Ab = &As[bc][0];
        const _Float16* Bb = &Bs[bc][0];

        half8 af[4], bf[4];
#pragma unroll
        for (int i = 0; i < 4; i++) {
            af[i] = *(const half8*)(Ab + (wm + i * 16 + l15) * 32 + xk8);
            bf[i] = *(const half8*)(Bb + (wn + i * 16 + l15) * 32 + xk8);
        }

        if (kt + 2 < nkt) {
            int bs = bc + 2; if (bs >= 3) bs -= 3;
            STAGE_TILE(bs, kt + 2);
        }

        __builtin_amdgcn_s_setprio(1);
#pragma unroll
        for (int i = 0; i < 4; i++)
#pragma unroll
            for (int j = 0; j < 4; j++)
                acc[i][j] = __builtin_amdgcn_mfma_f32_16x16x32_f16(af[i], bf[j], acc[i][j], 0, 0, 0);
        __builtin_amdgcn_s_setprio(0);

        if (kt + 1 < nkt) {
            if (kt + 2 < nkt) asm volatile("s_waitcnt vmcnt(4)" ::: "memory");
            else              asm volatile("s_waitcnt vmcnt(0)" ::: "memory");
            __builtin_amdgcn_s_barrier();
            __builtin_amdgcn_sched_barrier(0);
        }
        bc = bc + 1; if (bc == 3) bc = 0;
    }
#undef STAGE_TILE

    float bv[4];
#pragma unroll
    for (int j = 0; j < 4; j++) bv[j] = bias[n0 + wn + j * 16 + l15];

    const int ct = (int)(((n0 + wn) >> 6) % 6);

#pragma unroll
    for (int i = 0; i < 4; i++)
#pragma unroll
        for (int r = 0; r < 4; r++) {
            const size_t row = m0 + wm + i * 16 + quad * 4 + r;
            float v[4];
#pragma unroll
            for (int j = 0; j < 4; j++) v[j] = acc[i][j][r] + bv[j];

            if (MODE == 2 && ct != 5) {
                const float* tc = tab + (size_t)(row % S) * 64;
                const float ca = tc[l15],      sa = tc[32 + l15];
                const float cb = tc[16 + l15], sb = tc[48 + l15];
                const float qs = (ct < 4) ? QSCALE : 1.0f;
                const float n0v = v[0] * ca - v[2] * sa;
                const float n1v = v[1] * cb - v[3] * sb;
                const float n2v = v[2] * ca + v[0] * sa;
                const float n3v = v[3] * cb + v[1] * sb;
                v[0] = n0v * qs; v[1] = n1v * qs; v[2] = n2v * qs; v[3] = n3v * qs;
            }

            const size_t col = n0 + wn + l15;
#pragma unroll
            for (int j = 0; j < 4; j++) {
                if (MODE != 0) ((_Float16*)Cout)[row * N + col + j * 16] = (_Float16)v[j];
                else           ((float*)Cout)[row * N + col + j * 16] = v[j];
            }
        }
}

// ---------------------------------------------------------------------------
// V transpose: qkv V-chunks [token][g-chunk 64] -> vtg[(g*64 + d)*BS + token].
// (r10 fused-scatter variant was neutral-negative; separate kernel is final.)
// ---------------------------------------------------------------------------
__global__ __launch_bounds__(256)
void transpose_v_kernel(const _Float16* __restrict__ qkv, _Float16* __restrict__ vtg, int BS)
{
    __shared__ _Float16 tile[64 * 72];
    const int t = threadIdx.x;
    const int tb = blockIdx.x * 64;
    const int g = blockIdx.y;
    const int voff = (g * 6 + 5) * 64;

    const int tok = t >> 2, dsub = (t & 3) * 16;
    const _Float16* src = qkv + (size_t)(tb + tok) * QKV_DIM + voff + dsub;
    *(half8*)&tile[tok * 72 + dsub]     = *(const half8*)(src);
    *(half8*)&tile[tok * 72 + dsub + 8] = *(const half8*)(src + 8);
    __syncthreads();

    const int d = t >> 2, tsub = (t & 3) * 16;
    half8 a, c;
#pragma unroll
    for (int i = 0; i < 8; i++) a[i] = tile[(tsub + i) * 72 + d];
#pragma unroll
    for (int i = 0; i < 8; i++) c[i] = tile[(tsub + 8 + i) * 72 + d];
    _Float16* dst = vtg + ((size_t)g * 64 + d) * BS + tb + tsub;
    *(half8*)dst       = a;
    *(half8*)(dst + 8) = c;
}

// ---------------------------------------------------------------------------
// MFMA flash attention, no-max exp2 softmax, register-prefetched staging.
// r11: KVB=128 — r3's proven schedule (commit -> __syncthreads -> prefetch ->
// compute -> __syncthreads) with a 128-key staged tile: HALVES the barrier
// count (32 per block instead of 64) at identical per-key cost everywhere
// else. This layout passed correctness in r2; r2's regression was purely the
// __launch_bounds__(256,4) VGPR cap forcing spill — no cap here (~95 VGPR).
// Inner compute runs two 64-key halves per barrier pair, r3's per-s
// liveness-reduced softmax (T12 permlane P, constant ones-fragment L).
// LDS: Ks 128x72 (18.4KB) + VsT 64x136 (17.4KB) = 35.8KB.
// ---------------------------------------------------------------------------
__global__ __launch_bounds__(256)
void attn_mfma(const _Float16* __restrict__ qkv, const _Float16* __restrict__ vtg,
               _Float16* __restrict__ out, int B, int S)
{
    __shared__ _Float16 Ks[128 * 72];      // [key][d] stride 72
    __shared__ _Float16 VsT[64 * 136];     // [d][key] stride 136

    const int t = threadIdx.x, w = t >> 6, lane = t & 63;
    const int quad = lane >> 4, l15 = lane & 15;
    const int b = blockIdx.z, g = blockIdx.y;
    const int q0 = blockIdx.x * 32;
    const int qoff = (g * 6 + w) * 64;
    const int koff = (g * 6 + 4) * 64;

    // Q fragments: subtile s covers qrows q0+s*16 .. +16
    half8 qf[2][2];
#pragma unroll
    for (int s = 0; s < 2; s++) {
        const _Float16* qp = qkv + (size_t)(b * S + q0 + s * 16 + l15) * QKV_DIM + qoff;
        qf[s][0] = *(const half8*)(qp + quad * 8);
        qf[s][1] = *(const half8*)(qp + 32 + quad * 8);
    }

    // constant ones B-fragment for the L (row-sum) MFMA: col l15==0 only
    half8 lv;
    {
        const _Float16 one = (l15 == 0) ? (_Float16)1.0f : (_Float16)0.0f;
#pragma unroll
        for (int j = 0; j < 8; j++) lv[j] = one;
    }

    f32x4 O[2][4], L[2];
#pragma unroll
    for (int s = 0; s < 2; s++) {
        L[s] = (f32x4){0.f, 0.f, 0.f, 0.f};
#pragma unroll
        for (int dt = 0; dt < 4; dt++) O[s][dt] = (f32x4){0.f, 0.f, 0.f, 0.f};
    }

    // staging ownership (256 threads, 128-key tile; r2-verified addressing)
    const int kst_tok = t >> 1;            // K: token row 0..127
    const int kst_d   = (t & 1) * 32;      // K: d half (4 x half8)
    const int vst_d   = t >> 3;            // V^T: d rows vst_d and 32+vst_d
    const int vst_sub = (t & 7) * 16;      // V^T: key sub-chunk of 16 (2 x half8)

    const _Float16* kbase  = qkv + (size_t)(b * S + kst_tok) * QKV_DIM + koff + kst_d;
    const _Float16* vbase0 = vtg + ((size_t)g * 64 + vst_d) * (size_t)(B * S) + b * S + vst_sub;
    const _Float16* vbase1 = vtg + ((size_t)g * 64 + 32 + vst_d) * (size_t)(B * S) + b * S + vst_sub;

    // preload tile 0
    half8 kr[4], vr[4];
#pragma unroll
    for (int i = 0; i < 4; i++) kr[i] = *(const half8*)(kbase + i * 8);
    vr[0] = *(const half8*)(vbase0);
    vr[1] = *(const half8*)(vbase0 + 8);
    vr[2] = *(const half8*)(vbase1);
    vr[3] = *(const half8*)(vbase1 + 8);

    for (int kt = 0; kt < S; kt += 128) {
        // ---- commit staged registers to LDS ----
#pragma unroll
        for (int i = 0; i < 4; i++)
            *(half8*)&Ks[kst_tok * 72 + kst_d + i * 8] = kr[i];
        *(half8*)&VsT[vst_d * 136 + vst_sub]            = vr[0];
        *(half8*)&VsT[vst_d * 136 + vst_sub + 8]        = vr[1];
        *(half8*)&VsT[(32 + vst_d) * 136 + vst_sub]     = vr[2];
        *(half8*)&VsT[(32 + vst_d) * 136 + vst_sub + 8] = vr[3];
        __syncthreads();

        // ---- prefetch next tile (in flight during 2x compute halves) ----
        if (kt + 128 < S) {
#pragma unroll
            for (int i = 0; i < 4; i++)
                kr[i] = *(const half8*)(kbase + (size_t)(kt + 128) * QKV_DIM + i * 8);
            vr[0] = *(const half8*)(vbase0 + kt + 128);
            vr[1] = *(const half8*)(vbase0 + kt + 128 + 8);
            vr[2] = *(const half8*)(vbase1 + kt + 128);
            vr[3] = *(const half8*)(vbase1 + kt + 128 + 8);
        }

        // ---- two 64-key halves per staged tile ----
#pragma unroll
        for (int hb = 0; hb < 2; hb++) {
            const int kb = hb * 64;

            half8 kf[4][2];
#pragma unroll
            for (int mt = 0; mt < 4; mt++) {
                kf[mt][0] = *(const half8*)&Ks[(kb + mt * 16 + l15) * 72 + quad * 8];
                kf[mt][1] = *(const half8*)&Ks[(kb + mt * 16 + l15) * 72 + 32 + quad * 8];
            }

            half8 pf[2][2];
#pragma unroll
            for (int s = 0; s < 2; s++) {
                f32x4 sacc[4];
#pragma unroll
                for (int mt = 0; mt < 4; mt++) {
                    f32x4 z = (f32x4){0.f, 0.f, 0.f, 0.f};
                    z = __builtin_amdgcn_mfma_f32_16x16x32_f16(kf[mt][0], qf[s][0], z, 0, 0, 0);
                    z = __builtin_amdgcn_mfma_f32_16x16x32_f16(kf[mt][1], qf[s][1], z, 0, 0, 0);
                    sacc[mt] = z;
                }

                unsigned u[4][2];
#pragma unroll
                for (int mt = 0; mt < 4; mt++) {
                    fp16x2 pa = __builtin_amdgcn_cvt_pkrtz(fast_exp2(sacc[mt][0]),
                                                           fast_exp2(sacc[mt][1]));
                    fp16x2 pb = __builtin_amdgcn_cvt_pkrtz(fast_exp2(sacc[mt][2]),
                                                           fast_exp2(sacc[mt][3]));
                    u[mt][0] = __builtin_bit_cast(unsigned, pa);
                    u[mt][1] = __builtin_bit_cast(unsigned, pb);
                }

#pragma unroll
                for (int h = 0; h < 2; h++) {
                    uint32x4 pw;
#pragma unroll
                    for (int c = 0; c < 2; c++) {
                        unsigned x = u[h * 2][c], y = u[h * 2 + 1][c];
                        asm("v_permlane32_swap_b32 %0, %1" : "+v"(x), "+v"(y));
                        asm("v_permlane16_swap_b32 %0, %1" : "+v"(x), "+v"(y));
                        pw[c]     = x;   // F_A: words for src quads (quad&1)*2
                        pw[2 + c] = y;   // F_B: words for src quads (quad&1)*2+1
                    }
                    pf[s][h] = __builtin_bit_cast(half8, pw);
                }
            }

            // PV: O[qrow][d] += P.V ; L += P.ones
#pragma unroll
            for (int dt = 0; dt < 4; dt++) {
                half8 vv0 = *(const half8*)&VsT[(dt * 16 + l15) * 136 + kb + quad * 8];
                half8 vv1 = *(const half8*)&VsT[(dt * 16 + l15) * 136 + kb + 32 + quad * 8];
#pragma unroll
                for (int s = 0; s < 2; s++) {
                    O[s][dt] = __builtin_amdgcn_mfma_f32_16x16x32_f16(pf[s][0], vv0, O[s][dt], 0, 0, 0);
                    O[s][dt] = __builtin_amdgcn_mfma_f32_16x16x32_f16(pf[s][1], vv1, O[s][dt], 0, 0, 0);
                }
            }
#pragma unroll
            for (int s = 0; s < 2; s++) {
                L[s] = __builtin_amdgcn_mfma_f32_16x16x32_f16(pf[s][0], lv, L[s], 0, 0, 0);
                L[s] = __builtin_amdgcn_mfma_f32_16x16x32_f16(pf[s][1], lv, L[s], 0, 0, 0);
            }
        }
        __syncthreads();   // protect Ks/VsT before next staging
    }

    // ---- epilogue ----
    // l for qrow = quad*4+r lives at lane quad*16 (l15'=0), reg r.
    const int hq = g * 4 + w;
#pragma unroll
    for (int s = 0; s < 2; s++)
#pragma unroll
        for (int r = 0; r < 4; r++) {
            const float lr = __shfl(L[s][r], lane & 48, 64);
            const float ir = 1.0f / lr;
            const size_t row = (size_t)(b * S + q0 + s * 16 + quad * 4 + r);
#pragma unroll
            for (int dt = 0; dt < 4; dt++)
                out[row * (NHQ * HD) + hq * 64 + dt * 16 + l15] = (_Float16)(O[s][dt][r] * ir);
        }
}

// ---------------------------------------------------------------------------
extern "C" void kernel_launch(void* const* d_in, const int* in_sizes, int n_in,
                              void* d_out, int out_size, void* d_ws, size_t ws_size,
                              hipStream_t stream)
{
    const float* hidden = (const float*)d_in[0];
    const int*   pos    = (const int*)d_in[1];
    const float* qkv_w  = (const float*)d_in[2];
    const float* qkv_b  = (const float*)d_in[3];
    const float* o_w    = (const float*)d_in[4];
    const float* o_b    = (const float*)d_in[5];
    float* out = (float*)d_out;

    const int S  = in_sizes[1];                 // 2048
    const int BS = in_sizes[0] / MODEL_DIM;     // 4096
    const int B  = BS / S;                      // 2

    _Float16* hA   = (_Float16*)d_ws;                      // [BS, 2048]
    _Float16* hW1  = hA   + (size_t)BS * MODEL_DIM;        // [3072, 2048]
    _Float16* hW2  = hW1  + (size_t)QKV_DIM * MODEL_DIM;   // [2048, 2048]
    _Float16* qkvh = hW2  + (size_t)MODEL_DIM * MODEL_DIM; // [BS, 3072]
    _Float16* atth = qkvh + (size_t)BS * QKV_DIM;          // [BS, 2048]
    float*    tab  = (float*)(atth + (size_t)BS * MODEL_DIM); // [S, 64]
    _Float16* vtg  = (_Float16*)(tab + (size_t)S * 64);    // [NKV*64, BS]

    // 0) fused fp32 -> f16 converts + rope table (one launch)
    const int n0 = BS * MODEL_DIM / 4;
    const int n1 = QKV_DIM * MODEL_DIM / 4;
    const int n2 = MODEL_DIM * MODEL_DIM / 4;
    const int ns = S * 32;
    prep_kernel<<<(n0 + n1 + n2 + ns + 255) / 256, 256, 0, stream>>>(
        hidden, hA, n0, qkv_w, hW1, n1, o_w, hW2, n2, pos, tab, ns);

    // 1) QKV projection with fused RoPE (+0.125*log2e on Q)
    gemm_f16_mfma<2><<<dim3(QKV_DIM / 128, BS / 128), 256, 0, stream>>>(
        hA, hW1, qkv_b, qkvh, tab, BS, QKV_DIM, MODEL_DIM, S);

    // 1b) V transpose -> vtg
    transpose_v_kernel<<<dim3(BS / 64, NKV), 256, 0, stream>>>(qkvh, vtg, BS);

    // 2) Attention -> atth [BS, 2048]
    attn_mfma<<<dim3(S / 32, NKV, B), 256, 0, stream>>>(qkvh, vtg, atth, B, S);

    // 3) Output projection (fp32 out)
    gemm_f16_mfma<0><<<dim3(MODEL_DIM / 128, BS / 128), 256, 0, stream>>>(
        atth, hW2, o_b, out, nullptr, BS, MODEL_DIM, MODEL_DIM, S);
}